// Round 2
// baseline (342.950 us; speedup 1.0000x reference)
//
#include <hip/hip_runtime.h>
#include <hip/hip_bf16.h>

#define S_LEN 2048
#define NBATCH 2
#define DMODEL 1024
#define NHEAD 16
#define NKV 4
#define HDIM 64

typedef __attribute__((ext_vector_type(4))) float f32x4;
typedef __attribute__((ext_vector_type(8))) short s16x8;

__device__ __forceinline__ unsigned short f32_bf16(float f) {
    unsigned int u = __float_as_uint(f);
    u += 0x7FFFu + ((u >> 16) & 1u);
    return (unsigned short)(u >> 16);
}
__device__ __forceinline__ float bf16_f32(unsigned short h) {
    return __uint_as_float(((unsigned int)h) << 16);
}

// ---------------- f32 -> bf16 convert ----------------
__global__ __launch_bounds__(256) void cvt_bf16_k(const float* __restrict__ in,
                                                  unsigned short* __restrict__ out, int n4) {
    int i = blockIdx.x * 256 + threadIdx.x;
    if (i < n4) {
        const float4 v = reinterpret_cast<const float4*>(in)[i];
        ushort4 r;
        r.x = f32_bf16(v.x); r.y = f32_bf16(v.y);
        r.z = f32_bf16(v.z); r.w = f32_bf16(v.w);
        reinterpret_cast<ushort4*>(out)[i] = r;
    }
}

// ---------------- GEMM: C[M][N] = A[M][K] @ W[K][N], bf16 in, f32 acc ----------------
// EPI 0: f32 row-major out. EPI 1: rope + bf16 head-layout [B][nheads][S][DK].
// EPI 2: bf16 head-layout (no rope).
template<int EPI>
__global__ __launch_bounds__(256) void gemm_k(
    const unsigned short* __restrict__ A,
    const unsigned short* __restrict__ W,
    void* __restrict__ Out, int N, int K, int nheads)
{
    __shared__ unsigned short As[64][72];   // [m][k], +8 pad
    __shared__ unsigned short Bs[64][72];   // [n][k] (transposed), +8 pad

    const int tid  = threadIdx.x;
    const int lane = tid & 63;
    const int l15  = lane & 15;
    const int l4   = lane >> 4;
    const int wave = tid >> 6;
    const int wr   = (wave >> 1) * 32;
    const int wc   = (wave & 1) * 32;
    const int bm   = blockIdx.y * 64;
    const int bn   = blockIdx.x * 64;

    f32x4 acc[2][2] = {};

    for (int k0 = 0; k0 < K; k0 += 64) {
        #pragma unroll
        for (int cc = 0; cc < 2; ++cc) {
            const int c   = tid + cc * 256;      // 512 chunks of 8 elems
            const int row = c >> 3;
            const int col = (c & 7) * 8;
            *reinterpret_cast<s16x8*>(&As[row][col]) =
                *reinterpret_cast<const s16x8*>(A + (size_t)(bm + row) * K + k0 + col);
            const s16x8 wv =
                *reinterpret_cast<const s16x8*>(W + (size_t)(k0 + row) * N + bn + col);
            #pragma unroll
            for (int i = 0; i < 8; ++i) Bs[col + i][row] = (short)wv[i];
        }
        __syncthreads();
        #pragma unroll
        for (int ks = 0; ks < 2; ++ks) {
            s16x8 af[2], bfv[2];
            #pragma unroll
            for (int i = 0; i < 2; ++i)
                af[i] = *reinterpret_cast<const s16x8*>(&As[wr + i*16 + l15][ks*32 + l4*8]);
            #pragma unroll
            for (int j = 0; j < 2; ++j)
                bfv[j] = *reinterpret_cast<const s16x8*>(&Bs[wc + j*16 + l15][ks*32 + l4*8]);
            #pragma unroll
            for (int i = 0; i < 2; ++i)
                #pragma unroll
                for (int j = 0; j < 2; ++j)
                    acc[i][j] = __builtin_amdgcn_mfma_f32_16x16x32_bf16(
                        af[i], bfv[j], acc[i][j], 0, 0, 0);
        }
        __syncthreads();
    }

    #pragma unroll
    for (int i = 0; i < 2; ++i) {
        #pragma unroll
        for (int j = 0; j < 2; ++j) {
            #pragma unroll
            for (int v = 0; v < 4; ++v) {
                const int gr = bm + wr + i*16 + l4*4 + v;
                const int gc = bn + wc + j*16 + l15;
                float val = acc[i][j][v];
                if (EPI == 0) {
                    reinterpret_cast<float*>(Out)[(size_t)gr * N + gc] = val;
                } else {
                    if (EPI == 1) {
                        const float partner = __shfl_xor(val, 1, 64);
                        const int   jp = (gc & 63) >> 1;      // pair index 0..31
                        const int   hh = gc >> 6;             // head index
                        // inv_freq = 10000^(-2*jp/64)
                        const float inv = __expf((float)jp * (-2.0f / 64.0f) * 9.210340371976184f);
                        const float ang = (float)hh * inv;
                        float sn, cs;
                        __sincosf(ang, &sn, &cs);
                        val = ((gc & 1) == 0) ? (val * cs - partner * sn)
                                              : (partner * sn + val * cs);
                    }
                    const int b  = gr >> 11;       // / S_LEN
                    const int sr = gr & (S_LEN - 1);
                    const int hh = gc >> 6;
                    const int dk = gc & 63;
                    reinterpret_cast<unsigned short*>(Out)[
                        (((size_t)b * nheads + hh) * S_LEN + sr) * HDIM + dk] = f32_bf16(val);
                }
            }
        }
    }
}

// ---------------- flash attention (causal, GQA) ----------------
// Q: [B][NHEAD][S][DK] bf16 (rope applied), K: [B][NKV][S][DK], V: [B][NKV][S][DK]
// Ctx out: [B][S][NHEAD][DK] bf16
__global__ __launch_bounds__(256) void attn_k(
    const unsigned short* __restrict__ Q,
    const unsigned short* __restrict__ Kb,
    const unsigned short* __restrict__ Vb,
    unsigned short* __restrict__ Ctx)
{
    __shared__ unsigned short Plds[4][16][40];  // per-wave P tile [q16][kv32], pad->40

    const int tid  = threadIdx.x;
    const int lane = tid & 63;
    const int l15  = lane & 15;
    const int l4   = lane >> 4;
    const int wave = tid >> 6;

    const int qb0 = blockIdx.x * 64;
    const int h   = blockIdx.y;
    const int b   = blockIdx.z;
    const int g   = h >> 2;   // kv head

    const unsigned short* Qp = Q  + ((size_t)b * NHEAD + h) * S_LEN * HDIM;
    const unsigned short* Kp = Kb + ((size_t)b * NKV  + g) * S_LEN * HDIM;
    const unsigned short* Vp = Vb + ((size_t)b * NKV  + g) * S_LEN * HDIM;

    const int qb = qb0 + wave * 16;   // this wave's 16 q-rows

    // Q fragments (held in regs for whole KV loop)
    s16x8 qf[2];
    #pragma unroll
    for (int ks = 0; ks < 2; ++ks)
        qf[ks] = *reinterpret_cast<const s16x8*>(Qp + (size_t)(qb + l15) * HDIM + ks*32 + l4*8);

    f32x4 o[4] = {};
    float m[4], lsum[4];
    #pragma unroll
    for (int v = 0; v < 4; ++v) { m[v] = -1e30f; lsum[v] = 0.0f; }

    const int kvend = qb + 16;   // causal: max kv index needed is qb+15

    for (int kv0 = 0; kv0 < kvend; kv0 += 32) {
        // ---- scores: S[16q][32kv] = Q @ K^T, two 16-col chunks ----
        f32x4 s[2] = {};
        #pragma unroll
        for (int c = 0; c < 2; ++c) {
            #pragma unroll
            for (int ks = 0; ks < 2; ++ks) {
                const s16x8 kf = *reinterpret_cast<const s16x8*>(
                    Kp + (size_t)(kv0 + c*16 + l15) * HDIM + ks*32 + l4*8);
                s[c] = __builtin_amdgcn_mfma_f32_16x16x32_bf16(qf[ks], kf, s[c], 0, 0, 0);
            }
        }
        // ---- mask + online softmax ----
        #pragma unroll
        for (int v = 0; v < 4; ++v) {
            const int qg = qb + l4*4 + v;
            #pragma unroll
            for (int c = 0; c < 2; ++c) {
                const int kvg = kv0 + c*16 + l15;
                const float sv = s[c][v] * 0.125f;
                s[c][v] = (kvg <= qg) ? sv : -1e30f;
            }
            float mx = fmaxf(s[0][v], s[1][v]);
            #pragma unroll
            for (int off = 1; off < 16; off <<= 1)
                mx = fmaxf(mx, __shfl_xor(mx, off, 64));
            const float mnew  = fmaxf(m[v], mx);
            const float scale = __expf(m[v] - mnew);
            float psum = 0.0f;
            #pragma unroll
            for (int c = 0; c < 2; ++c) {
                const float p = __expf(s[c][v] - mnew);
                s[c][v] = p;
                psum += p;
            }
            #pragma unroll
            for (int off = 1; off < 16; off <<= 1)
                psum += __shfl_xor(psum, off, 64);
            lsum[v] = lsum[v] * scale + psum;
            m[v] = mnew;
            #pragma unroll
            for (int dkc = 0; dkc < 4; ++dkc) o[dkc][v] *= scale;
        }
        // ---- P (D-layout) -> LDS -> A-frag layout ----
        #pragma unroll
        for (int c = 0; c < 2; ++c)
            #pragma unroll
            for (int v = 0; v < 4; ++v)
                Plds[wave][l4*4 + v][c*16 + l15] = f32_bf16(s[c][v]);
        const s16x8 pa = *reinterpret_cast<const s16x8*>(&Plds[wave][l15][l4*8]);
        // ---- PV: O[16q][64dk] += P[16][32] @ V[32][64] ----
        #pragma unroll
        for (int dkc = 0; dkc < 4; ++dkc) {
            s16x8 vf;
            #pragma unroll
            for (int i = 0; i < 8; ++i)
                vf[i] = (short)Vp[(size_t)(kv0 + l4*8 + i) * HDIM + dkc*16 + l15];
            o[dkc] = __builtin_amdgcn_mfma_f32_16x16x32_bf16(pa, vf, o[dkc], 0, 0, 0);
        }
    }

    // ---- normalize + store ctx [B][S][NHEAD][DK] bf16 ----
    #pragma unroll
    for (int dkc = 0; dkc < 4; ++dkc) {
        #pragma unroll
        for (int v = 0; v < 4; ++v) {
            const int qg = qb + l4*4 + v;
            const int dk = dkc*16 + l15;
            const float val = o[dkc][v] / lsum[v];
            Ctx[(((size_t)b * S_LEN + qg) * NHEAD + h) * HDIM + dk] = f32_bf16(val);
        }
    }
}

// ---------------- launch ----------------
// Workspace layout (ushorts). NOTE: Ctx ALIASES xb — xb is dead after the
// three QKV GEMMs (stream-ordered before attn_k), so attention's output
// reuses its storage. Total ws: 12,058,624 ushorts = 23.0 MiB (was 33 MiB,
// which overflowed ws_size and stomped adjacent device buffers -> post-timing
// divergence in R1).
extern "C" void kernel_launch(void* const* d_in, const int* in_sizes, int n_in,
                              void* d_out, int out_size, void* d_ws, size_t ws_size,
                              hipStream_t stream) {
    const float* x  = (const float*)d_in[0];
    const float* wq = (const float*)d_in[1];
    const float* wk = (const float*)d_in[2];
    const float* wv = (const float*)d_in[3];
    const float* wo = (const float*)d_in[4];
    float* out = (float*)d_out;

    const int M = NBATCH * S_LEN;          // 4096
    const int nX  = M * DMODEL;            // 4194304
    const int nWq = DMODEL * NHEAD * HDIM; // 1048576
    const int nWk = DMODEL * NKV * HDIM;   // 262144
    const int nWo = DMODEL * DMODEL;       // 1048576
    const int nQ  = NBATCH * NHEAD * S_LEN * HDIM;  // 4194304
    const int nKV = NBATCH * NKV * S_LEN * HDIM;    // 1048576

    unsigned short* xb  = (unsigned short*)d_ws;
    unsigned short* wqb = xb  + nX;
    unsigned short* wkb = wqb + nWq;
    unsigned short* wvb = wkb + nWk;
    unsigned short* wob = wvb + nWk;
    unsigned short* Qb  = wob + nWo;
    unsigned short* Kb  = Qb  + nQ;
    unsigned short* Vbuf= Kb  + nKV;
    unsigned short* Ctx = xb;              // alias: xb dead after QKV GEMMs

    // convert to bf16
    cvt_bf16_k<<<nX  / 1024, 256, 0, stream>>>(x,  xb,  nX  / 4);
    cvt_bf16_k<<<nWq / 1024, 256, 0, stream>>>(wq, wqb, nWq / 4);
    cvt_bf16_k<<<nWk / 1024, 256, 0, stream>>>(wk, wkb, nWk / 4);
    cvt_bf16_k<<<nWk / 1024, 256, 0, stream>>>(wv, wvb, nWk / 4);
    cvt_bf16_k<<<nWo / 1024, 256, 0, stream>>>(wo, wob, nWo / 4);

    // QKV projections (+rope on Q,K), head-layout bf16 out
    gemm_k<1><<<dim3((NHEAD*HDIM)/64, M/64), 256, 0, stream>>>(xb, wqb, Qb,   NHEAD*HDIM, DMODEL, NHEAD);
    gemm_k<1><<<dim3((NKV*HDIM)/64,  M/64), 256, 0, stream>>>(xb, wkb, Kb,   NKV*HDIM,  DMODEL, NKV);
    gemm_k<2><<<dim3((NKV*HDIM)/64,  M/64), 256, 0, stream>>>(xb, wvb, Vbuf, NKV*HDIM,  DMODEL, NKV);

    // attention (writes Ctx, which reuses xb's storage)
    attn_k<<<dim3(S_LEN/64, NHEAD, NBATCH), 256, 0, stream>>>(Qb, Kb, Vbuf, Ctx);

    // output projection -> f32
    gemm_k<0><<<dim3(DMODEL/64, M/64), 256, 0, stream>>>(Ctx, wob, out, DMODEL, DMODEL, 0);
}